// Round 2
// baseline (440.557 us; speedup 1.0000x reference)
//
#include <hip/hip_runtime.h>
#include <hip/hip_bf16.h>

// B=2, L=2048, hidden=2048, H=16, KV=4, D=128, WIN=512
// Pipeline:
//   1) cast x, Wq|Wk|Wv (fused), Wo to bf16
//   2) qkv = x @ Wqkv^T        (m97-style MFMA GEMM, global_load_lds w=16)
//   3) RMSNorm(q,k)+RoPE scatter -> q[2,16,2048,128], k/v[2,4,2048,128]
//   3b) transpose V -> VT[2,4,128,2048]
//   4) sliding-window flash attention (DMA-staged K/VT, log2-domain softmax)
//   5) out = attn @ Wo^T       (fp32 out)

typedef unsigned short u16;
typedef unsigned int u32;
typedef __attribute__((ext_vector_type(8))) short bf16x8;
typedef __attribute__((ext_vector_type(4))) float f32x4;

#define AS1 __attribute__((address_space(1)))
#define AS3 __attribute__((address_space(3)))

__device__ __forceinline__ u16 f2b(float f) {
  union { float f; u32 u; } c; c.f = f;
  return (u16)((c.u + 0x8000u) >> 16);   // round-to-nearest (ties up); inputs bounded, no NaN/inf
}
__device__ __forceinline__ float b2f(u16 u) {
  union { u32 u; float f; } c; c.u = ((u32)u) << 16; return c.f;
}

// ---------------- fp32 -> bf16 cast ----------------
__global__ __launch_bounds__(256) void cvt_f32_bf16(const float* __restrict__ src,
                                                    u16* __restrict__ dst, int n) {
  int i = (blockIdx.x * 256 + threadIdx.x) * 4;
  if (i >= n) return;
  float4 v = *(const float4*)(src + i);
  ushort4 o;
  o.x = f2b(v.x); o.y = f2b(v.y); o.z = f2b(v.z); o.w = f2b(v.w);
  *(ushort4*)(dst + i) = o;
}

// ---------------- bf16 GEMM: C[M,N] = A[M,K] @ B[N,K]^T (m97 structure) ----
// 128x128 tile, BK=64, 4 waves (2x2), 4x4 16x16x32 MFMAs per wave.
// LDS unpadded [128][64]; staged via global_load_lds width=16.
// LDS byte offset of element (row,col)=row*128+col*2 = idx*16 where
// idx=p*256+tid, row=idx>>3, col=(idx&7)*8  -> wave base p*4096+w*1024+lane*16.
template<int F32OUT>
__global__ __launch_bounds__(256) void gemm_bt(const u16* __restrict__ A,
                                               const u16* __restrict__ Bm,
                                               void* __restrict__ C,
                                               int M, int N, int K) {
  __shared__ u16 As[128][64];
  __shared__ u16 Bs[128][64];
  const int tid  = threadIdx.x;
  const int w    = tid >> 6, lane = tid & 63, quad = lane >> 4, l16 = lane & 15;
  const int wm   = w >> 1, wn = w & 1;
  const int m0   = blockIdx.y * 128, n0 = blockIdx.x * 128;

  f32x4 zero = {0.f, 0.f, 0.f, 0.f};
  f32x4 acc[4][4];
#pragma unroll
  for (int i = 0; i < 4; i++)
#pragma unroll
    for (int j = 0; j < 4; j++) acc[i][j] = zero;

  const int srow = ((tid & 63) >> 3);       // lane/8 within wave
  const int scol = (tid & 7) * 8;

  for (int k0 = 0; k0 < K; k0 += 64) {
#pragma unroll
    for (int p = 0; p < 4; ++p) {
      int row = p * 32 + w * 8 + srow;      // = (p*256+tid)>>3
      __builtin_amdgcn_global_load_lds(
          (const AS1 void*)(A + (size_t)(m0 + row) * K + k0 + scol),
          (AS3 void*)((char*)&As[0][0] + p * 4096 + w * 1024), 16, 0, 0);
      __builtin_amdgcn_global_load_lds(
          (const AS1 void*)(Bm + (size_t)(n0 + row) * K + k0 + scol),
          (AS3 void*)((char*)&Bs[0][0] + p * 4096 + w * 1024), 16, 0, 0);
    }
    __syncthreads();
#pragma unroll
    for (int kk = 0; kk < 64; kk += 32) {
      bf16x8 af[4], bfr[4];
#pragma unroll
      for (int i = 0; i < 4; i++)
        af[i] = *(const bf16x8*)&As[wm * 64 + i * 16 + l16][kk + quad * 8];
#pragma unroll
      for (int j = 0; j < 4; j++)
        bfr[j] = *(const bf16x8*)&Bs[wn * 64 + j * 16 + l16][kk + quad * 8];
#pragma unroll
      for (int i = 0; i < 4; i++)
#pragma unroll
        for (int j = 0; j < 4; j++)
          acc[i][j] = __builtin_amdgcn_mfma_f32_16x16x32_bf16(af[i], bfr[j], acc[i][j], 0, 0, 0);
    }
    __syncthreads();
  }

  // C/D layout: col=lane&15, row=quad*4+reg
#pragma unroll
  for (int i = 0; i < 4; i++) {
#pragma unroll
    for (int r = 0; r < 4; r++) {
      int gr = m0 + wm * 64 + i * 16 + quad * 4 + r;
#pragma unroll
      for (int j = 0; j < 4; j++) {
        int gc = n0 + wn * 64 + j * 16 + l16;
        if (F32OUT) ((float*)C)[(size_t)gr * N + gc] = acc[i][j][r];
        else        ((u16*)C)[(size_t)gr * N + gc]   = f2b(acc[i][j][r]);
      }
    }
  }
}

// ---------------- RMSNorm + RoPE + layout scatter ----------------
__global__ __launch_bounds__(256) void rmsrope(const u16* __restrict__ qkv,
                                               const float* __restrict__ cosT,
                                               const float* __restrict__ sinT,
                                               const float* __restrict__ qw,
                                               const float* __restrict__ kw,
                                               u16* __restrict__ qo,
                                               u16* __restrict__ ko,
                                               u16* __restrict__ vo) {
  int wid  = blockIdx.x * 4 + (threadIdx.x >> 6);
  int lane = threadIdx.x & 63;
  int r  = wid / 24;
  int hh = wid % 24;
  int b = r >> 11, l = r & 2047;
  int cb = hh < 16 ? hh * 128 : (hh < 20 ? 2048 + (hh - 16) * 128 : 2560 + (hh - 20) * 128);
  const u16* src = qkv + (size_t)r * 3072 + cb;
  float v0 = b2f(src[lane]);
  float v1 = b2f(src[lane + 64]);
  float o0, o1;
  if (hh < 20) {
    float ss = v0 * v0 + v1 * v1;
#pragma unroll
    for (int off = 1; off < 64; off <<= 1) ss += __shfl_xor(ss, off, 64);
    float inv = rsqrtf(ss * (1.0f / 128.0f) + 1e-6f);
    const float* wt = hh < 16 ? qw : kw;
    float n0 = v0 * inv * wt[lane];
    float n1 = v1 * inv * wt[lane + 64];
    float c0 = cosT[l * 128 + lane],      c1 = cosT[l * 128 + 64 + lane];
    float s0 = sinT[l * 128 + lane],      s1 = sinT[l * 128 + 64 + lane];
    o0 = n0 * c0 - n1 * s0;
    o1 = n1 * c1 + n0 * s1;
  } else { o0 = v0; o1 = v1; }
  u16* dst; size_t base;
  if (hh < 16)      { dst = qo; base = ((size_t)(b * 16 + hh)        * 2048 + l) * 128; }
  else if (hh < 20) { dst = ko; base = ((size_t)(b * 4 + (hh - 16))  * 2048 + l) * 128; }
  else              { dst = vo; base = ((size_t)(b * 4 + (hh - 20))  * 2048 + l) * 128; }
  dst[base + lane]      = f2b(o0);
  dst[base + 64 + lane] = f2b(o1);
}

// ---------------- V transpose: [8][2048][128] -> [8][128][2048] ----------
__global__ __launch_bounds__(256) void transpose_v(const u16* __restrict__ src,
                                                   u16* __restrict__ dst) {
  __shared__ u16 T[64][72];
  const int lt = blockIdx.x, dt = blockIdx.y, bh = blockIdx.z;
  const u16* s = src + (size_t)bh * 2048 * 128 + (size_t)lt * 64 * 128 + dt * 64;
  u16*       d = dst + (size_t)bh * 128 * 2048 + (size_t)dt * 64 * 2048 + lt * 64;
  const int t = threadIdx.x;
  const int row = t >> 3, c8 = (t & 7) * 8;
#pragma unroll
  for (int p = 0; p < 2; ++p)
    *(uint4*)&T[p * 32 + row][c8] = *(const uint4*)(s + (size_t)(p * 32 + row) * 128 + c8);
  __syncthreads();
#pragma unroll
  for (int p = 0; p < 2; ++p) {
    int dr = p * 32 + row;
    u16 o[8];
#pragma unroll
    for (int j = 0; j < 8; ++j) o[j] = T[c8 + j][dr];
    *(uint4*)(d + (size_t)dr * 2048 + c8) = *(uint4*)o;
  }
}

// ---------------- sliding-window flash attention ----------------
// Block: 64 q-rows x head x batch; 4 waves, wave w owns q rows w*16..+15.
// K tile [64 keys][128 d] unpadded (DMA), VT tile [128 d][64 keys] unpadded (DMA).
// Softmax in log2 domain. P via per-wave padded LDS (C->A layout round-trip).
__global__ __launch_bounds__(256) void flash_swa(const u16* __restrict__ Q,
                                                 const u16* __restrict__ Kg,
                                                 const u16* __restrict__ VTg,
                                                 u16* __restrict__ Og) {
  constexpr int L = 2048, D = 128;
  __shared__ u16 Ks[64][128];
  __shared__ u16 Vt[128][64];
  __shared__ u16 Ps[4][16][72];

  const int q0  = blockIdx.x * 64;
  const int h   = blockIdx.y;
  const int b   = blockIdx.z;
  const int tid = threadIdx.x;
  const int w = tid >> 6, lane = tid & 63, quad = lane >> 4, l16 = lane & 15;
  const int kvh = h >> 2;

  const u16* Qb  = Q   + (size_t)(b * 16 + h)  * L * D;
  const u16* Kb  = Kg  + (size_t)(b * 4 + kvh) * L * D;
  const u16* VTb = VTg + (size_t)(b * 4 + kvh) * D * L;

  bf16x8 qf[4];
  {
    int qr = q0 + w * 16 + l16;
#pragma unroll
    for (int ks = 0; ks < 4; ++ks)
      qf[ks] = *(const bf16x8*)(Qb + (size_t)qr * D + ks * 32 + quad * 8);
  }

  f32x4 zero = {0.f, 0.f, 0.f, 0.f};
  f32x4 o[8];
#pragma unroll
  for (int i = 0; i < 8; i++) o[i] = zero;
  float mrow[4], lrow[4];
#pragma unroll
  for (int r = 0; r < 4; r++) { mrow[r] = -1e30f; lrow[r] = 0.f; }

  const float sscale = 0.08838834764831845f * 1.4426950408889634f;  // 1/sqrt(128)*log2(e)

  int kt0   = q0 > 512 ? q0 - 512 : 0;
  int ktend = q0 + 64 + 512; if (ktend > L) ktend = L;

  const int srow8 = (lane >> 3);        // lane/8
  const int scol8 = (lane & 7) * 8;
  const int srow16 = (lane >> 4);       // lane/16 (for K tile: 16 chunks/row)
  const int scol16 = (lane & 15) * 8;

  for (int kt = kt0; kt < ktend; kt += 64) {
    // K tile: LDS byte ofs (row,col)=row*256+col*2 = idx*16, idx=p*256+tid,
    // row=idx>>4, col=(idx&15)*8
#pragma unroll
    for (int p = 0; p < 4; ++p) {
      int row = p * 16 + w * 4 + srow16;
      __builtin_amdgcn_global_load_lds(
          (const AS1 void*)(Kb + (size_t)(kt + row) * D + scol16),
          (AS3 void*)((char*)&Ks[0][0] + p * 4096 + w * 1024), 16, 0, 0);
    }
    // VT tile: LDS byte ofs (row,col)=row*128+col*2 = idx*16, row=idx>>3, col=(idx&7)*8
#pragma unroll
    for (int p = 0; p < 4; ++p) {
      int row = p * 32 + w * 8 + srow8;
      __builtin_amdgcn_global_load_lds(
          (const AS1 void*)(VTb + (size_t)row * L + kt + scol8),
          (AS3 void*)((char*)&Vt[0][0] + p * 4096 + w * 1024), 16, 0, 0);
    }
    __syncthreads();

    // ---- S = Q K^T ----
    f32x4 s[4];
#pragma unroll
    for (int ct = 0; ct < 4; ct++) s[ct] = zero;
#pragma unroll
    for (int ks = 0; ks < 4; ++ks) {
#pragma unroll
      for (int ct = 0; ct < 4; ++ct) {
        bf16x8 kf = *(const bf16x8*)&Ks[ct * 16 + l16][ks * 32 + quad * 8];
        s[ct] = __builtin_amdgcn_mfma_f32_16x16x32_bf16(qf[ks], kf, s[ct], 0, 0, 0);
      }
    }

    // ---- scale (log2 domain) + window mask ----
    bool need_mask = (kt + 448 < q0) || (kt > q0 + 448);
    float sv[4][4];
#pragma unroll
    for (int ct = 0; ct < 4; ct++)
#pragma unroll
      for (int r = 0; r < 4; r++) {
        float x = s[ct][r] * sscale;
        if (need_mask) {
          int ki = kt + ct * 16 + l16;
          int qi = q0 + w * 16 + quad * 4 + r;
          int dd = qi - ki; if (dd < 0) dd = -dd;
          if (dd > 512) x = -__builtin_inff();
        }
        sv[ct][r] = x;
      }

    // ---- online softmax (log2 domain) ----
    float mt[4];
#pragma unroll
    for (int r = 0; r < 4; r++) {
      float v = fmaxf(fmaxf(sv[0][r], sv[1][r]), fmaxf(sv[2][r], sv[3][r]));
#pragma unroll
      for (int off = 1; off < 16; off <<= 1) v = fmaxf(v, __shfl_xor(v, off, 16));
      mt[r] = v;
    }
    float alpha[4], mnew[4];
#pragma unroll
    for (int r = 0; r < 4; r++) {
      mnew[r]  = fmaxf(mrow[r], mt[r]);
      alpha[r] = exp2f(mrow[r] - mnew[r]);
    }
    float psum[4] = {0.f, 0.f, 0.f, 0.f};
#pragma unroll
    for (int ct = 0; ct < 4; ct++)
#pragma unroll
      for (int r = 0; r < 4; r++) {
        float p = exp2f(sv[ct][r] - mnew[r]);
        psum[r] += p;
        Ps[w][quad * 4 + r][ct * 16 + l16] = f2b(p);
      }
#pragma unroll
    for (int r = 0; r < 4; r++) {
      float v = psum[r];
#pragma unroll
      for (int off = 1; off < 16; off <<= 1) v += __shfl_xor(v, off, 16);
      lrow[r] = lrow[r] * alpha[r] + v;
      mrow[r] = mnew[r];
    }
#pragma unroll
    for (int dt = 0; dt < 8; dt++)
#pragma unroll
      for (int r = 0; r < 4; r++) o[dt][r] *= alpha[r];

    // ---- O += P V ----
    bf16x8 pf[2];
#pragma unroll
    for (int ks2 = 0; ks2 < 2; ++ks2)
      pf[ks2] = *(const bf16x8*)&Ps[w][l16][ks2 * 32 + quad * 8];
#pragma unroll
    for (int dt = 0; dt < 8; ++dt) {
#pragma unroll
      for (int ks2 = 0; ks2 < 2; ++ks2) {
        bf16x8 vf = *(const bf16x8*)&Vt[dt * 16 + l16][ks2 * 32 + quad * 8];
        o[dt] = __builtin_amdgcn_mfma_f32_16x16x32_bf16(pf[ks2], vf, o[dt], 0, 0, 0);
      }
    }
    __syncthreads();
  }

  // ---- epilogue ----
#pragma unroll
  for (int r = 0; r < 4; r++) {
    float inv = 1.0f / lrow[r];
    int qr = q0 + w * 16 + quad * 4 + r;
    size_t base = ((size_t)(b * L + qr)) * 2048 + h * 128;
#pragma unroll
    for (int dt = 0; dt < 8; dt++)
      Og[base + dt * 16 + l16] = f2b(o[dt][r] * inv);
  }
}

// ---------------- launch ----------------
extern "C" void kernel_launch(void* const* d_in, const int* in_sizes, int n_in,
                              void* d_out, int out_size, void* d_ws, size_t ws_size,
                              hipStream_t stream) {
  const float* x    = (const float*)d_in[0];
  const float* cosT = (const float*)d_in[1];
  const float* sinT = (const float*)d_in[2];
  const float* Wq   = (const float*)d_in[3];
  const float* Wk   = (const float*)d_in[4];
  const float* Wv   = (const float*)d_in[5];
  const float* Wo   = (const float*)d_in[6];
  const float* qw   = (const float*)d_in[7];
  const float* kw   = (const float*)d_in[8];

  char* ws = (char*)d_ws;
  u16* x_bf    = (u16*)(ws + 0);          // 16 MB  [4096,2048]
  u16* wqkv_bf = (u16*)(ws + 16777216);   // 12 MB  [3072,2048]  (dead after gemm1)
  u16* wo_bf   = (u16*)(ws + 29360128);   //  8 MB  [2048,2048]
  u16* qkv_bf  = (u16*)(ws + 37748736);   // 24 MB  [4096,3072]
  u16* q_bf    = (u16*)(ws + 62914560);   // 16 MB  [2,16,2048,128]
  u16* k_bf    = (u16*)(ws + 79691776);   //  4 MB  [2,4,2048,128]
  u16* v_bf    = (u16*)(ws + 83886080);   //  4 MB  [2,4,2048,128]
  u16* vt_bf   = wqkv_bf;                 //  4 MB  [2,4,128,2048] (reuses wqkv)
  u16* attn_bf = x_bf;                    // 16 MB  [4096,2048]    (reuses x)

  cvt_f32_bf16<<<8192, 256, 0, stream>>>(x,  x_bf,    8388608);
  cvt_f32_bf16<<<4096, 256, 0, stream>>>(Wq, wqkv_bf, 4194304);
  cvt_f32_bf16<<<1024, 256, 0, stream>>>(Wk, wqkv_bf + 2048 * 2048,              1048576);
  cvt_f32_bf16<<<1024, 256, 0, stream>>>(Wv, wqkv_bf + 2048 * 2048 + 512 * 2048, 1048576);
  cvt_f32_bf16<<<4096, 256, 0, stream>>>(Wo, wo_bf,   4194304);

  gemm_bt<0><<<dim3(24, 32), 256, 0, stream>>>(x_bf, wqkv_bf, qkv_bf, 4096, 3072, 2048);
  rmsrope<<<24576, 256, 0, stream>>>(qkv_bf, cosT, sinT, qw, kw, q_bf, k_bf, v_bf);
  transpose_v<<<dim3(32, 2, 8), 256, 0, stream>>>(v_bf, vt_bf);
  flash_swa<<<dim3(32, 16, 2), 256, 0, stream>>>(q_bf, k_bf, vt_bf, attn_bf);
  gemm_bt<1><<<dim3(16, 32), 256, 0, stream>>>(attn_bf, wo_bf, d_out, 4096, 2048, 2048);
}

// Round 3
// 345.008 us; speedup vs baseline: 1.2769x; 1.2769x over previous
//
#include <hip/hip_runtime.h>
#include <hip/hip_bf16.h>

// B=2, L=2048, hidden=2048, H=16, KV=4, D=128, WIN=512
// Pipeline:
//   1) fused cast x, Wq|Wk|Wv, Wo -> bf16 (one kernel)
//   2) qkv = x @ Wqkv^T   (MFMA GEMM, global_load_lds w=16, XOR-swizzled LDS)
//   3) RMSNorm(q,k)+RoPE scatter; q pre-scaled by 1/sqrt(D)*log2(e)
//   3b) transpose V (read from qkv) -> VT[2,4,128,2048]
//   4) sliding-window flash attention (padded manual LDS staging, log2 softmax)
//   5) out = attn @ Wo^T  (fp32 out)

typedef unsigned short u16;
typedef unsigned int u32;
typedef __attribute__((ext_vector_type(8))) short bf16x8;
typedef __attribute__((ext_vector_type(4))) float f32x4;

#define AS1 __attribute__((address_space(1)))
#define AS3 __attribute__((address_space(3)))

__device__ __forceinline__ u16 f2b(float f) {
  union { float f; u32 u; } c; c.f = f;
  return (u16)((c.u + 0x8000u) >> 16);   // fast round; inputs bounded, no NaN/inf
}
__device__ __forceinline__ float b2f(u16 u) {
  union { u32 u; float f; } c; c.u = ((u32)u) << 16; return c.f;
}

// ---------------- fused fp32 -> bf16 casts ----------------
// 1024 elems/block: x:0..8191, Wq:8192..12287, Wk:12288..13311,
// Wv:13312..14335, Wo:14336..18431
__global__ __launch_bounds__(256) void cvt_all(const float* __restrict__ x,
                                               const float* __restrict__ wq,
                                               const float* __restrict__ wk,
                                               const float* __restrict__ wv,
                                               const float* __restrict__ wo,
                                               u16* __restrict__ xb,
                                               u16* __restrict__ wqkvb,
                                               u16* __restrict__ wob) {
  int blk = blockIdx.x;
  const float* s; u16* d; int off;
  if (blk < 8192)       { s = x;  d = xb;              off = blk * 1024; }
  else if (blk < 12288) { s = wq; d = wqkvb;           off = (blk - 8192) * 1024; }
  else if (blk < 13312) { s = wk; d = wqkvb + 4194304; off = (blk - 12288) * 1024; }
  else if (blk < 14336) { s = wv; d = wqkvb + 5242880; off = (blk - 13312) * 1024; }
  else                  { s = wo; d = wob;             off = (blk - 14336) * 1024; }
  int i = off + threadIdx.x * 4;
  float4 v = *(const float4*)(s + i);
  ushort4 o;
  o.x = f2b(v.x); o.y = f2b(v.y); o.z = f2b(v.z); o.w = f2b(v.w);
  *(ushort4*)(d + i) = o;
}

// ---------------- bf16 GEMM: C[M,N] = A[M,K] @ B[N,K]^T --------------------
// 128x128 tile, BK=64, 4 waves (2x2), 4x4 16x16x32 MFMAs per wave.
// global_load_lds width=16 into XOR-swizzled [128][64] LDS:
//   LDS (row, chunk c') holds global chunk c = c' ^ (row & 7)  (chunk = 8 u16)
//   DMA: lane fetches global chunk (lane&7)^(lane>>3); LDS dest = base+lane*16
//   read: chunk' = ((kk>>3)+quad) ^ (l16&7)  -> conflict-free ds_read_b128
template<int F32OUT>
__global__ __launch_bounds__(256) void gemm_bt(const u16* __restrict__ A,
                                               const u16* __restrict__ Bm,
                                               void* __restrict__ C,
                                               int M, int N, int K) {
  __shared__ u16 As[128][64];
  __shared__ u16 Bs[128][64];
  const int tid  = threadIdx.x;
  const int w    = tid >> 6, lane = tid & 63, quad = lane >> 4, l16 = lane & 15;
  const int wm   = w >> 1, wn = w & 1;
  const int m0   = blockIdx.y * 128, n0 = blockIdx.x * 128;

  f32x4 zero = {0.f, 0.f, 0.f, 0.f};
  f32x4 acc[4][4];
#pragma unroll
  for (int i = 0; i < 4; i++)
#pragma unroll
    for (int j = 0; j < 4; j++) acc[i][j] = zero;

  const int srow = lane >> 3;                      // row within 8-row group
  const int swz8 = ((lane & 7) ^ (lane >> 3)) * 8; // swizzled global col offset

  for (int k0 = 0; k0 < K; k0 += 64) {
#pragma unroll
    for (int p = 0; p < 4; ++p) {
      int row = p * 32 + w * 8 + srow;
      __builtin_amdgcn_global_load_lds(
          (const AS1 void*)(A + (size_t)(m0 + row) * K + k0 + swz8),
          (AS3 void*)((char*)&As[0][0] + p * 4096 + w * 1024), 16, 0, 0);
      __builtin_amdgcn_global_load_lds(
          (const AS1 void*)(Bm + (size_t)(n0 + row) * K + k0 + swz8),
          (AS3 void*)((char*)&Bs[0][0] + p * 4096 + w * 1024), 16, 0, 0);
    }
    __syncthreads();
#pragma unroll
    for (int kk = 0; kk < 64; kk += 32) {
      const int cs = ((kk >> 3) + quad) ^ (l16 & 7);
      bf16x8 af[4], bfr[4];
#pragma unroll
      for (int i = 0; i < 4; i++)
        af[i] = *(const bf16x8*)((const char*)&As[0][0] +
                                 (wm * 64 + i * 16 + l16) * 128 + cs * 16);
#pragma unroll
      for (int j = 0; j < 4; j++)
        bfr[j] = *(const bf16x8*)((const char*)&Bs[0][0] +
                                  (wn * 64 + j * 16 + l16) * 128 + cs * 16);
#pragma unroll
      for (int i = 0; i < 4; i++)
#pragma unroll
        for (int j = 0; j < 4; j++)
          acc[i][j] = __builtin_amdgcn_mfma_f32_16x16x32_bf16(af[i], bfr[j], acc[i][j], 0, 0, 0);
    }
    __syncthreads();
  }

  // C/D layout: col=lane&15, row=quad*4+reg
#pragma unroll
  for (int i = 0; i < 4; i++) {
#pragma unroll
    for (int r = 0; r < 4; r++) {
      int gr = m0 + wm * 64 + i * 16 + quad * 4 + r;
#pragma unroll
      for (int j = 0; j < 4; j++) {
        int gc = n0 + wn * 64 + j * 16 + l16;
        if (F32OUT) ((float*)C)[(size_t)gr * N + gc] = acc[i][j][r];
        else        ((u16*)C)[(size_t)gr * N + gc]   = f2b(acc[i][j][r]);
      }
    }
  }
}

// ---------------- RMSNorm + RoPE + layout scatter (q,k only) ---------------
// One wave per (row, head 0..19). heads 0..15=q (pre-scaled), 16..19=k.
__global__ __launch_bounds__(256) void rmsrope(const u16* __restrict__ qkv,
                                               const float* __restrict__ cosT,
                                               const float* __restrict__ sinT,
                                               const float* __restrict__ qw,
                                               const float* __restrict__ kw,
                                               u16* __restrict__ qo,
                                               u16* __restrict__ ko) {
  int wid  = blockIdx.x * 4 + (threadIdx.x >> 6);
  int lane = threadIdx.x & 63;
  int r  = wid / 20;
  int hh = wid % 20;
  int b = r >> 11, l = r & 2047;
  int cb = hh < 16 ? hh * 128 : 2048 + (hh - 16) * 128;
  const u16* src = qkv + (size_t)r * 3072 + cb;
  float v0 = b2f(src[lane]);
  float v1 = b2f(src[lane + 64]);
  float ss = v0 * v0 + v1 * v1;
#pragma unroll
  for (int off = 1; off < 64; off <<= 1) ss += __shfl_xor(ss, off, 64);
  float inv = rsqrtf(ss * (1.0f / 128.0f) + 1e-6f);
  const float* wt = hh < 16 ? qw : kw;
  float n0 = v0 * inv * wt[lane];
  float n1 = v1 * inv * wt[lane + 64];
  float c0 = cosT[l * 128 + lane],      c1 = cosT[l * 128 + 64 + lane];
  float s0 = sinT[l * 128 + lane],      s1 = sinT[l * 128 + 64 + lane];
  float o0 = n0 * c0 - n1 * s0;
  float o1 = n1 * c1 + n0 * s1;
  const float qscale = 0.08838834764831845f * 1.4426950408889634f; // 1/sqrt(D)*log2e
  u16* dst; size_t base;
  if (hh < 16) { dst = qo; base = ((size_t)(b * 16 + hh) * 2048 + l) * 128;
                 o0 *= qscale; o1 *= qscale; }
  else         { dst = ko; base = ((size_t)(b * 4 + (hh - 16)) * 2048 + l) * 128; }
  dst[base + lane]      = f2b(o0);
  dst[base + 64 + lane] = f2b(o1);
}

// -------- V transpose from qkv: v cols 2560.. -> VT[2,4,128,2048] ----------
__global__ __launch_bounds__(256) void transpose_v(const u16* __restrict__ qkv,
                                                   u16* __restrict__ dst) {
  __shared__ u16 T[64][72];
  const int lt = blockIdx.x, dt = blockIdx.y, bh = blockIdx.z;  // bh=b*4+kv
  const int b = bh >> 2, kv = bh & 3;
  const u16* s = qkv + ((size_t)(b * 2048 + lt * 64)) * 3072 + 2560 + kv * 128 + dt * 64;
  u16*       d = dst + (size_t)bh * 128 * 2048 + (size_t)dt * 64 * 2048 + lt * 64;
  const int t = threadIdx.x;
  const int row = t >> 3, c8 = (t & 7) * 8;
#pragma unroll
  for (int p = 0; p < 2; ++p)
    *(uint4*)&T[p * 32 + row][c8] = *(const uint4*)(s + (size_t)(p * 32 + row) * 3072 + c8);
  __syncthreads();
#pragma unroll
  for (int p = 0; p < 2; ++p) {
    int dr = p * 32 + row;
    u16 o[8];
#pragma unroll
    for (int j = 0; j < 8; ++j) o[j] = T[c8 + j][dr];
    *(uint4*)(d + (size_t)dr * 2048 + c8) = *(uint4*)o;
  }
}

// ---------------- sliding-window flash attention ----------------
// 64 q-rows x head x batch; 4 waves, wave w owns q rows w*16..+15.
// Padded LDS (conflict-free): Ks[64][136], Vt[128][72], Ps[4][16][72].
// Q pre-scaled by 1/sqrt(D)*log2e; softmax in log2 domain (exp2f).
__global__ __launch_bounds__(256) void flash_swa(const u16* __restrict__ Q,
                                                 const u16* __restrict__ Kg,
                                                 const u16* __restrict__ VTg,
                                                 u16* __restrict__ Og) {
  constexpr int L = 2048, D = 128;
  __shared__ u16 Ks[64][136];
  __shared__ u16 Vt[128][72];
  __shared__ u16 Ps[4][16][72];

  const int q0  = blockIdx.x * 64;
  const int h   = blockIdx.y;
  const int b   = blockIdx.z;
  const int tid = threadIdx.x;
  const int w = tid >> 6, lane = tid & 63, quad = lane >> 4, l16 = lane & 15;
  const int kvh = h >> 2;

  const u16* Qb  = Q   + (size_t)(b * 16 + h)  * L * D;
  const u16* Kb  = Kg  + (size_t)(b * 4 + kvh) * L * D;
  const u16* VTb = VTg + (size_t)(b * 4 + kvh) * D * L;

  bf16x8 qf[4];
  {
    int qr = q0 + w * 16 + l16;
#pragma unroll
    for (int ks = 0; ks < 4; ++ks)
      qf[ks] = *(const bf16x8*)(Qb + (size_t)qr * D + ks * 32 + quad * 8);
  }

  f32x4 zero = {0.f, 0.f, 0.f, 0.f};
  f32x4 o[8];
#pragma unroll
  for (int i = 0; i < 8; i++) o[i] = zero;
  float mrow[4], lrow[4];
#pragma unroll
  for (int r = 0; r < 4; r++) { mrow[r] = -1e30f; lrow[r] = 0.f; }

  int kt0   = q0 > 512 ? q0 - 512 : 0;
  int ktend = q0 + 64 + 512; if (ktend > L) ktend = L;

  for (int kt = kt0; kt < ktend; kt += 64) {
    // ---- stage K tile [64 keys][128 d], padded ----
#pragma unroll
    for (int p = 0; p < 4; ++p) {
      int c = tid + p * 256;
      int row = c >> 4, c8 = (c & 15) * 8;
      *(uint4*)&Ks[row][c8] = *(const uint4*)(Kb + (size_t)(kt + row) * D + c8);
    }
    // ---- stage VT tile [128 d][64 keys], padded (VT pre-transposed) ----
#pragma unroll
    for (int p = 0; p < 4; ++p) {
      int c = tid + p * 256;
      int row = c >> 3, c8 = (c & 7) * 8;
      *(uint4*)&Vt[row][c8] = *(const uint4*)(VTb + (size_t)row * L + kt + c8);
    }
    __syncthreads();

    // ---- S = Q K^T (16q x 64k per wave); scale already in Q ----
    f32x4 s[4];
#pragma unroll
    for (int ct = 0; ct < 4; ct++) s[ct] = zero;
#pragma unroll
    for (int ks = 0; ks < 4; ++ks) {
#pragma unroll
      for (int ct = 0; ct < 4; ++ct) {
        bf16x8 kf = *(const bf16x8*)&Ks[ct * 16 + l16][ks * 32 + quad * 8];
        s[ct] = __builtin_amdgcn_mfma_f32_16x16x32_bf16(qf[ks], kf, s[ct], 0, 0, 0);
      }
    }

    // ---- window mask (only edge tiles) ----
    bool need_mask = (kt + 448 < q0) || (kt > q0 + 448);
    float sv[4][4];
#pragma unroll
    for (int ct = 0; ct < 4; ct++)
#pragma unroll
      for (int r = 0; r < 4; r++) {
        float x = s[ct][r];
        if (need_mask) {
          int ki = kt + ct * 16 + l16;
          int qi = q0 + w * 16 + quad * 4 + r;
          int dd = qi - ki; if (dd < 0) dd = -dd;
          if (dd > 512) x = -__builtin_inff();
        }
        sv[ct][r] = x;
      }

    // ---- online softmax (log2 domain) ----
    float mt[4];
#pragma unroll
    for (int r = 0; r < 4; r++) {
      float v = fmaxf(fmaxf(sv[0][r], sv[1][r]), fmaxf(sv[2][r], sv[3][r]));
#pragma unroll
      for (int off = 1; off < 16; off <<= 1) v = fmaxf(v, __shfl_xor(v, off, 16));
      mt[r] = v;
    }
    float alpha[4], mnew[4];
#pragma unroll
    for (int r = 0; r < 4; r++) {
      mnew[r]  = fmaxf(mrow[r], mt[r]);
      alpha[r] = exp2f(mrow[r] - mnew[r]);
    }
    float psum[4] = {0.f, 0.f, 0.f, 0.f};
#pragma unroll
    for (int ct = 0; ct < 4; ct++)
#pragma unroll
      for (int r = 0; r < 4; r++) {
        float p = exp2f(sv[ct][r] - mnew[r]);
        psum[r] += p;
        Ps[w][quad * 4 + r][ct * 16 + l16] = f2b(p);
      }
#pragma unroll
    for (int r = 0; r < 4; r++) {
      float v = psum[r];
#pragma unroll
      for (int off = 1; off < 16; off <<= 1) v += __shfl_xor(v, off, 16);
      lrow[r] = lrow[r] * alpha[r] + v;
      mrow[r] = mnew[r];
    }
#pragma unroll
    for (int dt = 0; dt < 8; dt++)
#pragma unroll
      for (int r = 0; r < 4; r++) o[dt][r] *= alpha[r];

    // ---- O += P V ----
    bf16x8 pf[2];
#pragma unroll
    for (int ks2 = 0; ks2 < 2; ++ks2)
      pf[ks2] = *(const bf16x8*)&Ps[w][l16][ks2 * 32 + quad * 8];
#pragma unroll
    for (int dt = 0; dt < 8; ++dt) {
#pragma unroll
      for (int ks2 = 0; ks2 < 2; ++ks2) {
        bf16x8 vf = *(const bf16x8*)&Vt[dt * 16 + l16][ks2 * 32 + quad * 8];
        o[dt] = __builtin_amdgcn_mfma_f32_16x16x32_bf16(pf[ks2], vf, o[dt], 0, 0, 0);
      }
    }
    __syncthreads();
  }

  // ---- epilogue ----
#pragma unroll
  for (int r = 0; r < 4; r++) {
    float inv = 1.0f / lrow[r];
    int qr = q0 + w * 16 + quad * 4 + r;
    size_t base = ((size_t)(b * L + qr)) * 2048 + h * 128;
#pragma unroll
    for (int dt = 0; dt < 8; dt++)
      Og[base + dt * 16 + l16] = f2b(o[dt][r] * inv);
  }
}

// ---------------- launch ----------------
extern "C" void kernel_launch(void* const* d_in, const int* in_sizes, int n_in,
                              void* d_out, int out_size, void* d_ws, size_t ws_size,
                              hipStream_t stream) {
  const float* x    = (const float*)d_in[0];
  const float* cosT = (const float*)d_in[1];
  const float* sinT = (const float*)d_in[2];
  const float* Wq   = (const float*)d_in[3];
  const float* Wk   = (const float*)d_in[4];
  const float* Wv   = (const float*)d_in[5];
  const float* Wo   = (const float*)d_in[6];
  const float* qw   = (const float*)d_in[7];
  const float* kw   = (const float*)d_in[8];

  char* ws = (char*)d_ws;
  u16* x_bf    = (u16*)(ws + 0);          // 16 MB  [4096,2048]
  u16* wqkv_bf = (u16*)(ws + 16777216);   // 12 MB  [3072,2048]  (dead after gemm1)
  u16* wo_bf   = (u16*)(ws + 29360128);   //  8 MB  [2048,2048]
  u16* qkv_bf  = (u16*)(ws + 37748736);   // 24 MB  [4096,3072]
  u16* q_bf    = (u16*)(ws + 62914560);   // 16 MB  [2,16,2048,128]
  u16* k_bf    = (u16*)(ws + 79691776);   //  4 MB  [2,4,2048,128]
  u16* vt_bf   = wqkv_bf;                 //  4 MB  [2,4,128,2048] (reuses wqkv)
  u16* attn_bf = x_bf;                    // 16 MB  [4096,2048]    (reuses x)

  cvt_all<<<18432, 256, 0, stream>>>(x, Wq, Wk, Wv, Wo, x_bf, wqkv_bf, wo_bf);
  gemm_bt<0><<<dim3(24, 32), 256, 0, stream>>>(x_bf, wqkv_bf, qkv_bf, 4096, 3072, 2048);
  rmsrope<<<20480, 256, 0, stream>>>(qkv_bf, cosT, sinT, qw, kw, q_bf, k_bf);
  transpose_v<<<dim3(32, 2, 8), 256, 0, stream>>>(qkv_bf, vt_bf);
  flash_swa<<<dim3(32, 16, 2), 256, 0, stream>>>(q_bf, k_bf, vt_bf, attn_bf);
  gemm_bt<1><<<dim3(16, 32), 256, 0, stream>>>(attn_bf, wo_bf, d_out, 4096, 2048, 2048);
}

// Round 4
// 312.431 us; speedup vs baseline: 1.4101x; 1.1043x over previous
//
#include <hip/hip_runtime.h>
#include <hip/hip_bf16.h>

// B=2, L=2048, hidden=2048, H=16, KV=4, D=128, WIN=512
// Pipeline:
//   1) fused cast x, Wq|Wk|Wv, Wo -> bf16 (one kernel)
//   2) qkv = x @ Wqkv^T   (MFMA GEMM, global_load_lds w=16, XOR-swizzled LDS)
//   3) RMSNorm(q,k)+RoPE scatter; q pre-scaled by 1/sqrt(D)*log2(e)
//   3b) transpose V (read from qkv) -> VT[2,4,128,2048]
//   4) sliding-window flash attention, S^T dataflow:
//      - S^T = K·(Q-frag) per 16x16x32 MFMA (lane q=l16, k=ct*16+quad*4+r)
//      - no max subtraction (scores bounded: |s*log2e/sqrtD| <= 16.4)
//      - in-lane psum + 2 shuffles; P packed b64 into LDS A-layout
//   5) out = attn @ Wo^T  (fp32 out)

typedef unsigned short u16;
typedef unsigned int u32;
typedef __attribute__((ext_vector_type(8))) short bf16x8;
typedef __attribute__((ext_vector_type(4))) float f32x4;

#define AS1 __attribute__((address_space(1)))
#define AS3 __attribute__((address_space(3)))

__device__ __forceinline__ u16 f2b(float f) {
  union { float f; u32 u; } c; c.f = f;
  return (u16)((c.u + 0x8000u) >> 16);   // fast round; inputs bounded, no NaN/inf
}
__device__ __forceinline__ float b2f(u16 u) {
  union { u32 u; float f; } c; c.u = ((u32)u) << 16; return c.f;
}

// ---------------- fused fp32 -> bf16 casts ----------------
__global__ __launch_bounds__(256) void cvt_all(const float* __restrict__ x,
                                               const float* __restrict__ wq,
                                               const float* __restrict__ wk,
                                               const float* __restrict__ wv,
                                               const float* __restrict__ wo,
                                               u16* __restrict__ xb,
                                               u16* __restrict__ wqkvb,
                                               u16* __restrict__ wob) {
  int blk = blockIdx.x;
  const float* s; u16* d; int off;
  if (blk < 8192)       { s = x;  d = xb;              off = blk * 1024; }
  else if (blk < 12288) { s = wq; d = wqkvb;           off = (blk - 8192) * 1024; }
  else if (blk < 13312) { s = wk; d = wqkvb + 4194304; off = (blk - 12288) * 1024; }
  else if (blk < 14336) { s = wv; d = wqkvb + 5242880; off = (blk - 13312) * 1024; }
  else                  { s = wo; d = wob;             off = (blk - 14336) * 1024; }
  int i = off + threadIdx.x * 4;
  float4 v = *(const float4*)(s + i);
  ushort4 o;
  o.x = f2b(v.x); o.y = f2b(v.y); o.z = f2b(v.z); o.w = f2b(v.w);
  *(ushort4*)(d + i) = o;
}

// ---------------- bf16 GEMM: C[M,N] = A[M,K] @ B[N,K]^T --------------------
// 128x128 tile, BK=64, 4 waves (2x2), 4x4 16x16x32 MFMAs per wave.
// global_load_lds width=16 into XOR-swizzled [128][64] LDS.
template<int F32OUT>
__global__ __launch_bounds__(256) void gemm_bt(const u16* __restrict__ A,
                                               const u16* __restrict__ Bm,
                                               void* __restrict__ C,
                                               int M, int N, int K) {
  __shared__ u16 As[128][64];
  __shared__ u16 Bs[128][64];
  const int tid  = threadIdx.x;
  const int w    = tid >> 6, lane = tid & 63, quad = lane >> 4, l16 = lane & 15;
  const int wm   = w >> 1, wn = w & 1;
  const int m0   = blockIdx.y * 128, n0 = blockIdx.x * 128;

  f32x4 zero = {0.f, 0.f, 0.f, 0.f};
  f32x4 acc[4][4];
#pragma unroll
  for (int i = 0; i < 4; i++)
#pragma unroll
    for (int j = 0; j < 4; j++) acc[i][j] = zero;

  const int srow = lane >> 3;
  const int swz8 = ((lane & 7) ^ (lane >> 3)) * 8;

  for (int k0 = 0; k0 < K; k0 += 64) {
#pragma unroll
    for (int p = 0; p < 4; ++p) {
      int row = p * 32 + w * 8 + srow;
      __builtin_amdgcn_global_load_lds(
          (const AS1 void*)(A + (size_t)(m0 + row) * K + k0 + swz8),
          (AS3 void*)((char*)&As[0][0] + p * 4096 + w * 1024), 16, 0, 0);
      __builtin_amdgcn_global_load_lds(
          (const AS1 void*)(Bm + (size_t)(n0 + row) * K + k0 + swz8),
          (AS3 void*)((char*)&Bs[0][0] + p * 4096 + w * 1024), 16, 0, 0);
    }
    __syncthreads();
#pragma unroll
    for (int kk = 0; kk < 64; kk += 32) {
      const int cs = ((kk >> 3) + quad) ^ (l16 & 7);
      bf16x8 af[4], bfr[4];
#pragma unroll
      for (int i = 0; i < 4; i++)
        af[i] = *(const bf16x8*)((const char*)&As[0][0] +
                                 (wm * 64 + i * 16 + l16) * 128 + cs * 16);
#pragma unroll
      for (int j = 0; j < 4; j++)
        bfr[j] = *(const bf16x8*)((const char*)&Bs[0][0] +
                                  (wn * 64 + j * 16 + l16) * 128 + cs * 16);
#pragma unroll
      for (int i = 0; i < 4; i++)
#pragma unroll
        for (int j = 0; j < 4; j++)
          acc[i][j] = __builtin_amdgcn_mfma_f32_16x16x32_bf16(af[i], bfr[j], acc[i][j], 0, 0, 0);
    }
    __syncthreads();
  }

#pragma unroll
  for (int i = 0; i < 4; i++) {
#pragma unroll
    for (int r = 0; r < 4; r++) {
      int gr = m0 + wm * 64 + i * 16 + quad * 4 + r;
#pragma unroll
      for (int j = 0; j < 4; j++) {
        int gc = n0 + wn * 64 + j * 16 + l16;
        if (F32OUT) ((float*)C)[(size_t)gr * N + gc] = acc[i][j][r];
        else        ((u16*)C)[(size_t)gr * N + gc]   = f2b(acc[i][j][r]);
      }
    }
  }
}

// ---------------- RMSNorm + RoPE + layout scatter (q,k only) ---------------
__global__ __launch_bounds__(256) void rmsrope(const u16* __restrict__ qkv,
                                               const float* __restrict__ cosT,
                                               const float* __restrict__ sinT,
                                               const float* __restrict__ qw,
                                               const float* __restrict__ kw,
                                               u16* __restrict__ qo,
                                               u16* __restrict__ ko) {
  int wid  = blockIdx.x * 4 + (threadIdx.x >> 6);
  int lane = threadIdx.x & 63;
  int r  = wid / 20;
  int hh = wid % 20;
  int b = r >> 11, l = r & 2047;
  int cb = hh < 16 ? hh * 128 : 2048 + (hh - 16) * 128;
  const u16* src = qkv + (size_t)r * 3072 + cb;
  float v0 = b2f(src[lane]);
  float v1 = b2f(src[lane + 64]);
  float ss = v0 * v0 + v1 * v1;
#pragma unroll
  for (int off = 1; off < 64; off <<= 1) ss += __shfl_xor(ss, off, 64);
  float inv = rsqrtf(ss * (1.0f / 128.0f) + 1e-6f);
  const float* wt = hh < 16 ? qw : kw;
  float n0 = v0 * inv * wt[lane];
  float n1 = v1 * inv * wt[lane + 64];
  float c0 = cosT[l * 128 + lane],      c1 = cosT[l * 128 + 64 + lane];
  float s0 = sinT[l * 128 + lane],      s1 = sinT[l * 128 + 64 + lane];
  float o0 = n0 * c0 - n1 * s0;
  float o1 = n1 * c1 + n0 * s1;
  const float qscale = 0.08838834764831845f * 1.4426950408889634f; // 1/sqrt(D)*log2e
  u16* dst; size_t base;
  if (hh < 16) { dst = qo; base = ((size_t)(b * 16 + hh) * 2048 + l) * 128;
                 o0 *= qscale; o1 *= qscale; }
  else         { dst = ko; base = ((size_t)(b * 4 + (hh - 16)) * 2048 + l) * 128; }
  dst[base + lane]      = f2b(o0);
  dst[base + 64 + lane] = f2b(o1);
}

// -------- V transpose from qkv: v cols 2560.. -> VT[2,4,128,2048] ----------
__global__ __launch_bounds__(256) void transpose_v(const u16* __restrict__ qkv,
                                                   u16* __restrict__ dst) {
  __shared__ u16 T[64][72];
  const int lt = blockIdx.x, dt = blockIdx.y, bh = blockIdx.z;
  const int b = bh >> 2, kv = bh & 3;
  const u16* s = qkv + ((size_t)(b * 2048 + lt * 64)) * 3072 + 2560 + kv * 128 + dt * 64;
  u16*       d = dst + (size_t)bh * 128 * 2048 + (size_t)dt * 64 * 2048 + lt * 64;
  const int t = threadIdx.x;
  const int row = t >> 3, c8 = (t & 7) * 8;
#pragma unroll
  for (int p = 0; p < 2; ++p)
    *(uint4*)&T[p * 32 + row][c8] = *(const uint4*)(s + (size_t)(p * 32 + row) * 3072 + c8);
  __syncthreads();
#pragma unroll
  for (int p = 0; p < 2; ++p) {
    int dr = p * 32 + row;
    u16 o[8];
#pragma unroll
    for (int j = 0; j < 8; ++j) o[j] = T[c8 + j][dr];
    *(uint4*)(d + (size_t)dr * 2048 + c8) = *(uint4*)o;
  }
}

// ---------------- sliding-window flash attention (S^T dataflow) ------------
// 64 q-rows x head x batch; 4 waves, wave w owns q rows w*16..+15.
// S^T = K-frag(A) x Q-frag(B): lane holds S[q=l16][k=ct*16+quad*4+r].
// No max subtraction (RMSNorm => |s| <= 16.4 in log2 domain).
// P packed to Ps[q][k] via b64 writes; PV with P as A-operand (orig layout).
__global__ __launch_bounds__(256) void flash_swa(const u16* __restrict__ Q,
                                                 const u16* __restrict__ Kg,
                                                 const u16* __restrict__ VTg,
                                                 u16* __restrict__ Og) {
  constexpr int L = 2048, D = 128;
  __shared__ u16 Ks[64][136];
  __shared__ u16 Vt[128][72];
  __shared__ u16 Ps[4][16][72];

  const int q0  = blockIdx.x * 64;
  const int h   = blockIdx.y;
  const int b   = blockIdx.z;
  const int tid = threadIdx.x;
  const int w = tid >> 6, lane = tid & 63, quad = lane >> 4, l16 = lane & 15;
  const int kvh = h >> 2;

  const u16* Qb  = Q   + (size_t)(b * 16 + h)  * L * D;
  const u16* Kb  = Kg  + (size_t)(b * 4 + kvh) * L * D;
  const u16* VTb = VTg + (size_t)(b * 4 + kvh) * D * L;

  bf16x8 qf[4];
  {
    int qr = q0 + w * 16 + l16;
#pragma unroll
    for (int ks = 0; ks < 4; ++ks)
      qf[ks] = *(const bf16x8*)(Qb + (size_t)qr * D + ks * 32 + quad * 8);
  }
  const int qi = q0 + w * 16 + l16;   // this lane's q row (S^T dataflow)

  f32x4 zero = {0.f, 0.f, 0.f, 0.f};
  f32x4 o[8];
#pragma unroll
  for (int i = 0; i < 8; i++) o[i] = zero;
  float lrow = 0.f;

  int kt0   = q0 > 512 ? q0 - 512 : 0;
  int ktend = q0 + 64 + 512; if (ktend > L) ktend = L;

  for (int kt = kt0; kt < ktend; kt += 64) {
    // ---- stage K tile [64 keys][128 d], padded ----
#pragma unroll
    for (int p = 0; p < 4; ++p) {
      int c = tid + p * 256;
      int row = c >> 4, c8 = (c & 15) * 8;
      *(uint4*)&Ks[row][c8] = *(const uint4*)(Kb + (size_t)(kt + row) * D + c8);
    }
    // ---- stage VT tile [128 d][64 keys], padded ----
#pragma unroll
    for (int p = 0; p < 4; ++p) {
      int c = tid + p * 256;
      int row = c >> 3, c8 = (c & 7) * 8;
      *(uint4*)&Vt[row][c8] = *(const uint4*)(VTb + (size_t)row * L + kt + c8);
    }
    __syncthreads();

    // ---- S^T = K x Q^T : s[ct] tile rows=k, cols=q ----
    f32x4 s[4];
#pragma unroll
    for (int ct = 0; ct < 4; ct++) s[ct] = zero;
#pragma unroll
    for (int ks = 0; ks < 4; ++ks) {
#pragma unroll
      for (int ct = 0; ct < 4; ++ct) {
        bf16x8 kf = *(const bf16x8*)&Ks[ct * 16 + l16][ks * 32 + quad * 8];
        s[ct] = __builtin_amdgcn_mfma_f32_16x16x32_bf16(kf, qf[ks], s[ct], 0, 0, 0);
      }
    }

    // ---- P = exp2(S^T) (no max-sub), in-lane psum, pack to Ps[q][k] ----
    bool need_mask = (kt + 448 < q0) || (kt > q0 + 448);
    float psum = 0.f;
#pragma unroll
    for (int ct = 0; ct < 4; ct++) {
      u16 ph[4];
#pragma unroll
      for (int r = 0; r < 4; r++) {
        float x = s[ct][r];
        if (need_mask) {
          int ki = kt + ct * 16 + quad * 4 + r;
          int dd = qi - ki; if (dd < 0) dd = -dd;
          if (dd > 512) x = -__builtin_inff();
        }
        float p = exp2f(x);
        psum += p;
        ph[r] = f2b(p);
      }
      uint2 pk;
      pk.x = (u32)ph[0] | ((u32)ph[1] << 16);
      pk.y = (u32)ph[2] | ((u32)ph[3] << 16);
      *(uint2*)&Ps[w][l16][ct * 16 + quad * 4] = pk;
    }
    psum += __shfl_xor(psum, 16, 64);
    psum += __shfl_xor(psum, 32, 64);
    lrow += psum;

    // ---- O += P V  (P as A-operand from per-wave LDS; no barrier needed) --
    bf16x8 pf[2];
#pragma unroll
    for (int ks2 = 0; ks2 < 2; ++ks2)
      pf[ks2] = *(const bf16x8*)&Ps[w][l16][ks2 * 32 + quad * 8];
#pragma unroll
    for (int dt = 0; dt < 8; ++dt) {
#pragma unroll
      for (int ks2 = 0; ks2 < 2; ++ks2) {
        bf16x8 vf = *(const bf16x8*)&Vt[dt * 16 + l16][ks2 * 32 + quad * 8];
        o[dt] = __builtin_amdgcn_mfma_f32_16x16x32_bf16(pf[ks2], vf, o[dt], 0, 0, 0);
      }
    }
    __syncthreads();
  }

  // ---- epilogue: fetch lrow for this lane's output rows, store ----
#pragma unroll
  for (int r = 0; r < 4; r++) {
    float lv  = __shfl(lrow, (lane & 48) + quad * 4 + r, 64);
    float inv = 1.0f / lv;
    int qr = q0 + w * 16 + quad * 4 + r;
    size_t base = ((size_t)(b * L + qr)) * 2048 + h * 128;
#pragma unroll
    for (int dt = 0; dt < 8; dt++)
      Og[base + dt * 16 + l16] = f2b(o[dt][r] * inv);
  }
}

// ---------------- launch ----------------
extern "C" void kernel_launch(void* const* d_in, const int* in_sizes, int n_in,
                              void* d_out, int out_size, void* d_ws, size_t ws_size,
                              hipStream_t stream) {
  const float* x    = (const float*)d_in[0];
  const float* cosT = (const float*)d_in[1];
  const float* sinT = (const float*)d_in[2];
  const float* Wq   = (const float*)d_in[3];
  const float* Wk   = (const float*)d_in[4];
  const float* Wv   = (const float*)d_in[5];
  const float* Wo   = (const float*)d_in[6];
  const float* qw   = (const float*)d_in[7];
  const float* kw   = (const float*)d_in[8];

  char* ws = (char*)d_ws;
  u16* x_bf    = (u16*)(ws + 0);          // 16 MB  [4096,2048]
  u16* wqkv_bf = (u16*)(ws + 16777216);   // 12 MB  [3072,2048]  (dead after gemm1)
  u16* wo_bf   = (u16*)(ws + 29360128);   //  8 MB  [2048,2048]
  u16* qkv_bf  = (u16*)(ws + 37748736);   // 24 MB  [4096,3072]
  u16* q_bf    = (u16*)(ws + 62914560);   // 16 MB  [2,16,2048,128]
  u16* k_bf    = (u16*)(ws + 79691776);   //  4 MB  [2,4,2048,128]
  u16* vt_bf   = wqkv_bf;                 //  4 MB  [2,4,128,2048] (reuses wqkv)
  u16* attn_bf = x_bf;                    // 16 MB  [4096,2048]    (reuses x)

  cvt_all<<<18432, 256, 0, stream>>>(x, Wq, Wk, Wv, Wo, x_bf, wqkv_bf, wo_bf);
  gemm_bt<0><<<dim3(24, 32), 256, 0, stream>>>(x_bf, wqkv_bf, qkv_bf, 4096, 3072, 2048);
  rmsrope<<<20480, 256, 0, stream>>>(qkv_bf, cosT, sinT, qw, kw, q_bf, k_bf);
  transpose_v<<<dim3(32, 2, 8), 256, 0, stream>>>(qkv_bf, vt_bf);
  flash_swa<<<dim3(32, 16, 2), 256, 0, stream>>>(q_bf, k_bf, vt_bf, attn_bf);
  gemm_bt<1><<<dim3(16, 32), 256, 0, stream>>>(attn_bf, wo_bf, d_out, 4096, 2048, 2048);
}